// Round 3
// baseline (359.527 us; speedup 1.0000x reference)
//
#include <hip/hip_runtime.h>
#include <stdint.h>

#define BS 4
#define NN 1024
#define GD 6
#define CIN 256
#define NH 8
#define DH 32
#define HID 16
#define MCS 64

#define PG_ELEMS (BS*NN*NN*GD)                 // 25165824
#define OUT_OFF  PG_ELEMS
#define MASK_OFF (PG_ELEMS + BS*NN*CIN)        // 26214400

typedef float vfloat4 __attribute__((ext_vector_type(4)));
typedef float vfloat2 __attribute__((ext_vector_type(2)));
typedef unsigned vuint4 __attribute__((ext_vector_type(4)));

#if __has_builtin(__builtin_amdgcn_rcpf)
__device__ __forceinline__ float fast_rcp(float x) { return __builtin_amdgcn_rcpf(x); }
#else
__device__ __forceinline__ float fast_rcp(float x) { return 1.0f / x; }
#endif
#if __has_builtin(__builtin_amdgcn_exp2f)
__device__ __forceinline__ float fast_exp2(float x) { return __builtin_amdgcn_exp2f(x); }
#else
__device__ __forceinline__ float fast_exp2(float x) { return exp2f(x); }
#endif
#define LOG2E 1.44269504088896340736f

// swish via v_exp_f32 + v_rcp_f32 (avoids IEEE divide sequence)
__device__ __forceinline__ float swishf(float x) {
    return x * fast_rcp(1.0f + fast_exp2(x * -LOG2E));
}

// Fused 4096x256 @ 256x256 + bias GEMM; blockIdx.y selects one of up to 3 (W,b,dst).
// RPB = rows per block (16 for the 3-way launch, 8 for the single launch -> 2 blocks/CU).
template<int RPB>
__global__ __launch_bounds__(256) void gemm3(const float* __restrict__ X,
    const float* __restrict__ W0, const float* __restrict__ B0, float* __restrict__ D0,
    const float* __restrict__ W1, const float* __restrict__ B1, float* __restrict__ D1,
    const float* __restrict__ W2, const float* __restrict__ B2, float* __restrict__ D2)
{
    const float* W; const float* Bv; float* D;
    if (blockIdx.y == 0)      { W = W0; Bv = B0; D = D0; }
    else if (blockIdx.y == 1) { W = W1; Bv = B1; D = D1; }
    else                      { W = W2; Bv = B2; D = D2; }
    const int tid = threadIdx.x;
    const int c4  = tid & 63;        // column quad: cols 4*c4 .. 4*c4+3
    const int rg  = tid >> 6;        // row group
    const int r0  = blockIdx.x * RPB;
    constexpr int RG = RPB / 4;      // rows per row-group (4 or 2)

    __shared__ float xsT[CIN][RPB + 4];   // [k][row], padded
    {
        float tmp[RPB];
        #pragma unroll
        for (int r = 0; r < RPB; ++r) tmp[r] = X[(size_t)(r0 + r)*CIN + tid];
        #pragma unroll
        for (int j = 0; j < RPB/4; ++j)
            *(vfloat4*)&xsT[tid][4*j] = (vfloat4){tmp[4*j+0], tmp[4*j+1], tmp[4*j+2], tmp[4*j+3]};
    }
    __syncthreads();

    vfloat4 acc[RG];
    #pragma unroll
    for (int r = 0; r < RG; ++r) acc[r] = (vfloat4){0.f,0.f,0.f,0.f};
    const vfloat4* W4 = (const vfloat4*)W;
    #pragma unroll 4
    for (int k = 0; k < CIN; ++k) {
        vfloat4 w = W4[(size_t)k*64 + c4];                  // coalesced 1 KB/wave
        if constexpr (RG == 4) {
            vfloat4 xr = *(const vfloat4*)&xsT[k][rg*4];    // wave-uniform broadcast b128
            acc[0] += xr.x * w;
            acc[1] += xr.y * w;
            acc[2] += xr.z * w;
            acc[3] += xr.w * w;
        } else {
            vfloat2 xr = *(const vfloat2*)&xsT[k][rg*2];    // wave-uniform broadcast b64
            acc[0] += xr.x * w;
            acc[1] += xr.y * w;
        }
    }
    vfloat4 bb = ((const vfloat4*)Bv)[c4];
    vfloat4* D4 = (vfloat4*)D;
    const size_t rbase = (size_t)(r0 + rg*RG);
    #pragma unroll
    for (int r = 0; r < RG; ++r) D4[(rbase + r)*64 + c4] = acc[r] + bb;
}

// One block per (query i, batch b).
__global__ __launch_bounds__(256, 8) void attn_topk(
    const float* __restrict__ pg, const int* __restrict__ mask,
    const float* __restrict__ lW1g, const float* __restrict__ lb1g,
    const float* __restrict__ lW2g, const float* __restrict__ lb2g,
    const float* __restrict__ lW3g, const float* __restrict__ lb3g,
    const float* __restrict__ Q, const float* __restrict__ Kc, const float* __restrict__ Vc,
    float* __restrict__ O, float* __restrict__ pg_out, float* __restrict__ mask_out)
{
    const int i = blockIdx.x, b = blockIdx.y, tid = threadIdx.x;
    const int lane = tid & 63;

    // union: select phase -> dual hist[2][256] u32; eqlist aliases hist_B; later -> sc[64][8] f32
    __shared__ __align__(16) unsigned selbuf[512];   // 2 KB
    __shared__ float sg[MCS*7];                      // compact nbhd_g, stride 7
    __shared__ int nj[MCS];                          // bit31 = invalid flag
    __shared__ __align__(16) unsigned joff[MCS];     // float4 row offsets into Q/K/V space
    __shared__ vfloat4 obuf[4][64];                  // per-wave output partials (4 KB)
    __shared__ unsigned wsum[4];
    __shared__ unsigned sel_bin, sel_need, s_cnt, s_eqcnt;

    float (*sc)[NH]   = (float (*)[NH])selbuf;
    unsigned* eqlist  = selbuf + 256;

    const int* mrow = mask + b*NN;
    if (tid == 0) { mask_out[b*NN + i] = mrow[i] ? 1.0f : 0.0f; s_cnt = 0; s_eqcnt = 0; }

    const size_t rowoff = (size_t)(b*NN + i) * (NN*GD);
    const vfloat4* src4 = (const vfloat4*)(pg + rowoff);
    vfloat4* dst4 = (vfloat4*)(pg_out + rowoff);

    // prefetch Q row quad (channels 4q..4q+3) for feat phase
    vfloat4 q4 = ((const vfloat4*)Q)[(size_t)(b*NN + i)*64 + (tid & 63)];
    const int4 mv = ((const int4*)mrow)[tid];

    // ---- per-thread rows j=4t..4t+3: 6 consecutive float4, dist^2 in regs.
    //      pg is const __restrict__, so the compiler may rematerialize these loads
    //      at the compaction scatter instead of holding 24 regs across the radix. ----
    const vfloat4* gg = src4 + tid*6;
    vfloat4 g0 = gg[0], g1 = gg[1], g2 = gg[2], g3 = gg[3], g4 = gg[4], g5 = gg[5];
    float rv[4][6];
    rv[0][0]=g0.x; rv[0][1]=g0.y; rv[0][2]=g0.z; rv[0][3]=g0.w; rv[0][4]=g1.x; rv[0][5]=g1.y;
    rv[1][0]=g1.z; rv[1][1]=g1.w; rv[1][2]=g2.x; rv[1][3]=g2.y; rv[1][4]=g2.z; rv[1][5]=g2.w;
    rv[2][0]=g3.x; rv[2][1]=g3.y; rv[2][2]=g3.z; rv[2][3]=g3.w; rv[2][4]=g4.x; rv[2][5]=g4.y;
    rv[3][0]=g4.z; rv[3][1]=g4.w; rv[3][2]=g5.x; rv[3][3]=g5.y; rv[3][4]=g5.z; rv[3][5]=g5.w;
    const int vb[4] = { mv.x, mv.y, mv.z, mv.w };
    unsigned key[4];
    #pragma unroll
    for (int r = 0; r < 4; ++r) {
        float d2 = rv[r][0]*rv[r][0] + rv[r][1]*rv[r][1] + rv[r][2]*rv[r][2]
                 + rv[r][3]*rv[r][3] + rv[r][4]*rv[r][4] + rv[r][5]*rv[r][5];
        key[r] = __float_as_uint(vb[r] ? d2 : 1e30f);
    }

    // zero BOTH histogram buffers up front (dual-buffer: level L uses buf L&1,
    // each buf re-zeroed right after its read -> one barrier saved per level)
    selbuf[tid] = 0;
    selbuf[tid + 256] = 0;
    __syncthreads();                               // B0: zeroing + s_cnt/s_eqcnt visible

    // ---- 4-level radix select: find exact 64-smallest threshold (3 barriers/level) ----
    unsigned prefix = 0;
    int need = MCS;
    for (int level = 0; level < 4; ++level) {
        const int shift = 24 - 8*level;
        unsigned* hist = selbuf + ((level & 1) << 8);
        if (level == 0) {
            // digits cluster into few bins: ballot-clustered counting,
            // one atomic per distinct digit per wave.
            #pragma unroll
            for (int r = 0; r < 4; ++r) {
                unsigned d = key[r] >> 24;
                unsigned long long todo = __ballot(true);
                while (todo) {
                    int leader = (int)(__ffsll((unsigned long long)todo) - 1);
                    unsigned dl = __shfl(d, leader);
                    unsigned long long match = __ballot(d == dl);
                    if (lane == leader) atomicAdd(&hist[dl], (unsigned)__popcll(match));
                    todo &= ~match;
                }
            }
        } else {
            const unsigned pmask = 0xFFFFFFFFu << (shift + 8);
            #pragma unroll
            for (int r = 0; r < 4; ++r)
                if ((key[r] & pmask) == prefix)
                    atomicAdd(&hist[(key[r] >> shift) & 0xFFu], 1u);
        }
        __syncthreads();                           // B1: histogram complete
        unsigned own = hist[tid];
        hist[tid] = 0;                             // re-zero for level+2 (and eqlist)
        unsigned v = own;
        #pragma unroll
        for (int off = 1; off < 64; off <<= 1) {
            unsigned nv = __shfl_up(v, off);
            if (lane >= off) v += nv;
        }
        if (lane == 63) wsum[tid >> 6] = v;
        __syncthreads();                           // B2: wsum ready
        unsigned basec = 0;
        for (int w = 0; w < (tid >> 6); ++w) basec += wsum[w];
        unsigned incl = v + basec;
        unsigned excl = incl - own;
        if (excl < (unsigned)need && (unsigned)need <= incl) {
            sel_bin = (unsigned)tid;
            sel_need = (unsigned)need - excl;
        }
        __syncthreads();                           // B3: sel ready
        prefix |= (sel_bin << shift);
        need = (int)sel_need;
    }
    const unsigned T = prefix;
    const int needT = need;

    // ---- compaction: owners scatter selected rows straight into LDS ----
    #pragma unroll
    for (int r = 0; r < 4; ++r) {
        unsigned kk = key[r];
        int j = tid*4 + r;
        if (kk < T) {
            unsigned p = atomicAdd(&s_cnt, 1u);
            nj[p] = j | (vb[r] ? 0 : (int)0x80000000);
            #pragma unroll
            for (int g = 0; g < GD; ++g) sg[p*7 + g] = rv[r][g];
        } else if (kk == T) {
            unsigned e = atomicAdd(&s_eqcnt, 1u);
            if (e < 64) eqlist[e] = (unsigned)j;
        }
    }
    __syncthreads();                               // B5: nj[0..cbase) final
    const int cbase = (int)s_cnt;
    if (tid == 0) {
        int ec = (int)s_eqcnt; if (ec > 64) ec = 64;
        for (int s2 = 0; s2 < needT; ++s2) {
            int bi = -1, bj = 0x7FFFFFFF;
            for (int e = 0; e < ec; ++e) {
                int jj = (int)eqlist[e];
                if (jj < bj) { bj = jj; bi = e; }
            }
            if (bi >= 0) {
                eqlist[bi] = 0x7FFFFFFFu;
                nj[cbase + s2] = bj | (mrow[bj] ? 0 : (int)0x80000000);
            }
        }
    }
    __syncthreads();                               // B6: nj fully final
    // tie owners fill g-values; first 64 threads fill row offsets
    #pragma unroll
    for (int r = 0; r < 4; ++r) {
        if (key[r] == T) {
            int j = tid*4 + r;
            for (int s2 = 0; s2 < needT; ++s2)
                if ((nj[cbase + s2] & 0x7FFFFFFF) == j) {
                    #pragma unroll
                    for (int g = 0; g < GD; ++g) sg[(cbase + s2)*7 + g] = rv[r][g];
                }
        }
    }
    if (tid < MCS) joff[tid] = ((unsigned)(b*NN + (nj[tid] & 0x7FFFFFFF))) << 6;
    __syncthreads();                               // B7: sg + joff final; selbuf -> sc[][]

    // ---- feat dot-products into registers (loads issue NOW, consumed cheaply;
    //      the MLP below hides any residual gather latency). Lane q captures
    //      (m = 16p + 8*mc + (q&7), h = q>>3) in pack<mc>. ----
    const int q = tid & 63;
    const int p = tid >> 6;
    const int hh = q >> 3;
    q4 *= 0.17677669529663688f;                    // fold 1/sqrt(32) into q
    const vfloat4* Kc4 = (const vfloat4*)Kc;
    float pack0 = 0.f, pack1 = 0.f;
    {
        const vuint4* jo4 = (const vuint4*)(joff + (p << 4));
        vuint4 oa = jo4[0], ob = jo4[1], oc = jo4[2], od = jo4[3];
        #define FEAT_ONE(OFF, RR, PACK) do { \
            vfloat4 kv = Kc4[(OFF) + (unsigned)q]; \
            float d = q4.x * kv.x; \
            d = fmaf(q4.y, kv.y, d); \
            d = fmaf(q4.z, kv.z, d); \
            d = fmaf(q4.w, kv.w, d); \
            d += __shfl_xor(d, 1); \
            d += __shfl_xor(d, 2); \
            d += __shfl_xor(d, 4); \
            if ((q & 7) == (RR)) (PACK) = d; \
        } while (0)
        FEAT_ONE(oa.x, 0, pack0); FEAT_ONE(oa.y, 1, pack0);
        FEAT_ONE(oa.z, 2, pack0); FEAT_ONE(oa.w, 3, pack0);
        FEAT_ONE(ob.x, 4, pack0); FEAT_ONE(ob.y, 5, pack0);
        FEAT_ONE(ob.z, 6, pack0); FEAT_ONE(ob.w, 7, pack0);
        FEAT_ONE(oc.x, 0, pack1); FEAT_ONE(oc.y, 1, pack1);
        FEAT_ONE(oc.z, 2, pack1); FEAT_ONE(oc.w, 3, pack1);
        FEAT_ONE(od.x, 4, pack1); FEAT_ONE(od.y, 5, pack1);
        FEAT_ONE(od.z, 6, pack1); FEAT_ONE(od.w, 7, pack1);
        #undef FEAT_ONE
    }

    // ---- passthrough copy, deferred: L2/L3-warm re-read, NT store; registers
    //      transient (no radix-phase pressure). The MLP absorbs the vmcnt drain. ----
    #pragma unroll
    for (int t = 0; t < 6; ++t) {
        vfloat4 v = src4[tid + 256*t];
        __builtin_nontemporal_store(v, &dst4[tid + 256*t]);
    }

    __builtin_amdgcn_s_setprio(1);
    // ---- location-kernel MLP: wave-uniform head -> scalar (s_load) weights ----
    #pragma unroll
    for (int pass = 0; pass < 2; ++pass) {
        const int h = __builtin_amdgcn_readfirstlane((tid >> 6) + pass*4);   // 0..7
        const int m = lane;
        const float* W1h = lW1g + h*(GD*HID);
        const float* B1h = lb1g + h*HID;
        const float* W2h = lW2g + h*(HID*HID);
        const float* B2h = lb2g + h*HID;
        const float* W3h = lW3g + h*HID;
        float gv[GD];
        #pragma unroll
        for (int g = 0; g < GD; ++g) gv[g] = sg[m*7 + g];
        float h1[HID];
        #pragma unroll
        for (int kk = 0; kk < HID; ++kk) {
            float a = B1h[kk];
            #pragma unroll
            for (int g = 0; g < GD; ++g) a += gv[g] * W1h[g*HID + kk];
            h1[kk] = swishf(a);
        }
        float h2[HID];
        #pragma unroll
        for (int l = 0; l < HID; ++l) {
            float a = B2h[l];
            #pragma unroll
            for (int kk = 0; kk < HID; ++kk) a += h1[kk] * W2h[kk*HID + l];
            h2[l] = swishf(a);
        }
        float a3 = lb3g[h];
        #pragma unroll
        for (int kk = 0; kk < HID; ++kk) a3 += h2[kk] * W3h[kk];
        sc[m][h] = (nj[m] < 0) ? -1e38f : swishf(a3);
    }
    __syncthreads();                               // MLP's sc complete (drains NT stores too)

    // ---- merge feat partials: 2 conflict-free LDS adds (bijective lane->slot map) ----
    {
        float* scf = (float*)selbuf;
        const int a0 = p*128 + ((q & 7) << 3) + (q >> 3);
        scf[a0]      += pack0;                     // -1e38 rows stay -1e38
        scf[a0 + 64] += pack1;
    }
    __syncthreads();

    // ---- softmax over m, wave-parallel: lane = m, wave (x2 passes) = head ----
    #pragma unroll
    for (int pass = 0; pass < 2; ++pass) {
        int h = (tid >> 6) + pass*4;
        float s = sc[lane][h];
        float mx = s;
        #pragma unroll
        for (int off = 32; off; off >>= 1) mx = fmaxf(mx, __shfl_xor(mx, off));
        float e = fast_exp2((s - mx) * LOG2E);
        float sum = e;
        #pragma unroll
        for (int off = 32; off; off >>= 1) sum += __shfl_xor(sum, off);
        sc[lane][h] = e * fast_rcp(sum);
    }
    __syncthreads();

    // ---- out: wave p owns m = 16p..16p+15; coalesced float4 V loads; LDS reduce ----
    {
        const vfloat4* Vc4 = (const vfloat4*)Vc;
        const vuint4* jo4 = (const vuint4*)(joff + (p << 4));
        vuint4 oa = jo4[0], ob = jo4[1], oc = jo4[2], od = jo4[3];
        vfloat4 acc = (vfloat4){0.f,0.f,0.f,0.f};
        #define OUT_ONE(OFF, MM) do { \
            float a = sc[MM][hh]; \
            vfloat4 v4 = Vc4[(OFF) + (unsigned)q]; \
            acc += a * v4; \
        } while (0)
        const int mb = p << 4;
        OUT_ONE(oa.x, mb+0);  OUT_ONE(oa.y, mb+1);  OUT_ONE(oa.z, mb+2);  OUT_ONE(oa.w, mb+3);
        OUT_ONE(ob.x, mb+4);  OUT_ONE(ob.y, mb+5);  OUT_ONE(ob.z, mb+6);  OUT_ONE(ob.w, mb+7);
        OUT_ONE(oc.x, mb+8);  OUT_ONE(oc.y, mb+9);  OUT_ONE(oc.z, mb+10); OUT_ONE(oc.w, mb+11);
        OUT_ONE(od.x, mb+12); OUT_ONE(od.y, mb+13); OUT_ONE(od.z, mb+14); OUT_ONE(od.w, mb+15);
        #undef OUT_ONE
        __builtin_amdgcn_s_setprio(0);
        obuf[p][q] = acc;
    }
    __syncthreads();
    {
        const float* ob = (const float*)obuf;
        float s = ob[tid] + ob[256 + tid] + ob[512 + tid] + ob[768 + tid];
        O[(size_t)(b*NN + i)*CIN + tid] = s;
    }
}

extern "C" void kernel_launch(void* const* d_in, const int* in_sizes, int n_in,
                              void* d_out, int out_size, void* d_ws, size_t ws_size,
                              hipStream_t stream) {
    const float* pg   = (const float*)d_in[0];
    const float* x    = (const float*)d_in[1];
    const int*   mask = (const int*)d_in[2];
    const float* lW1  = (const float*)d_in[3];
    const float* lb1  = (const float*)d_in[4];
    const float* lW2  = (const float*)d_in[5];
    const float* lb2  = (const float*)d_in[6];
    const float* lW3  = (const float*)d_in[7];
    const float* lb3  = (const float*)d_in[8];
    const float* Wq   = (const float*)d_in[9];
    const float* bq   = (const float*)d_in[10];
    const float* Wk   = (const float*)d_in[11];
    const float* bk   = (const float*)d_in[12];
    const float* Wv   = (const float*)d_in[13];
    const float* bv   = (const float*)d_in[14];
    const float* Wo   = (const float*)d_in[15];
    const float* bo   = (const float*)d_in[16];

    float* out = (float*)d_out;
    float* Q  = (float*)d_ws;
    float* Kc = Q  + (size_t)BS*NN*CIN;
    float* Vc = Kc + (size_t)BS*NN*CIN;
    float* O  = Vc + (size_t)BS*NN*CIN;

    // QKV projections (z = 0,1,2)
    gemm3<16><<<dim3(BS*NN/16, 3), 256, 0, stream>>>(x, Wq, bq, Q, Wk, bk, Kc, Wv, bv, Vc);
    // top-k + attention (also performs the pairwise_g passthrough copy + mask write)
    attn_topk<<<dim3(NN, BS), 256, 0, stream>>>(pg, mask, lW1, lb1, lW2, lb2, lW3, lb3,
                                                Q, Kc, Vc, O, out, out + MASK_OFF);
    // output projection: 8 rows/block -> 512 blocks -> 2 blocks/CU (was 1, latency-exposed)
    gemm3<8><<<dim3(BS*NN/8, 1), 256, 0, stream>>>(O, Wo, bo, out + OUT_OFF,
                                                   Wo, bo, out + OUT_OFF,
                                                   Wo, bo, out + OUT_OFF);
}

// Round 4
// 329.495 us; speedup vs baseline: 1.0911x; 1.0911x over previous
//
#include <hip/hip_runtime.h>
#include <stdint.h>

#define BS 4
#define NN 1024
#define GD 6
#define CIN 256
#define NH 8
#define DH 32
#define HID 16
#define MCS 64

#define PG_ELEMS (BS*NN*NN*GD)                 // 25165824
#define OUT_OFF  PG_ELEMS
#define MASK_OFF (PG_ELEMS + BS*NN*CIN)        // 26214400

typedef float vfloat4 __attribute__((ext_vector_type(4)));
typedef float vfloat2 __attribute__((ext_vector_type(2)));
typedef unsigned vuint4 __attribute__((ext_vector_type(4)));

#if __has_builtin(__builtin_amdgcn_rcpf)
__device__ __forceinline__ float fast_rcp(float x) { return __builtin_amdgcn_rcpf(x); }
#else
__device__ __forceinline__ float fast_rcp(float x) { return 1.0f / x; }
#endif
#if __has_builtin(__builtin_amdgcn_exp2f)
__device__ __forceinline__ float fast_exp2(float x) { return __builtin_amdgcn_exp2f(x); }
#else
__device__ __forceinline__ float fast_exp2(float x) { return exp2f(x); }
#endif
#define LOG2E 1.44269504088896340736f

// swish via v_exp_f32 + v_rcp_f32 (avoids IEEE divide sequence)
__device__ __forceinline__ float swishf(float x) {
    return x * fast_rcp(1.0f + fast_exp2(x * -LOG2E));
}

// Fused 4096x256 @ 256x256 + bias GEMM; blockIdx.y selects one of up to 3 (W,b,dst).
// RPB = rows per block (16 for the 3-way launch, 8 for the single launch -> 2 blocks/CU).
template<int RPB>
__global__ __launch_bounds__(256) void gemm3(const float* __restrict__ X,
    const float* __restrict__ W0, const float* __restrict__ B0, float* __restrict__ D0,
    const float* __restrict__ W1, const float* __restrict__ B1, float* __restrict__ D1,
    const float* __restrict__ W2, const float* __restrict__ B2, float* __restrict__ D2)
{
    const float* W; const float* Bv; float* D;
    if (blockIdx.y == 0)      { W = W0; Bv = B0; D = D0; }
    else if (blockIdx.y == 1) { W = W1; Bv = B1; D = D1; }
    else                      { W = W2; Bv = B2; D = D2; }
    const int tid = threadIdx.x;
    const int c4  = tid & 63;        // column quad: cols 4*c4 .. 4*c4+3
    const int rg  = tid >> 6;        // row group
    const int r0  = blockIdx.x * RPB;
    constexpr int RG = RPB / 4;      // rows per row-group (4 or 2)

    __shared__ float xsT[CIN][RPB + 4];   // [k][row], padded
    {
        float tmp[RPB];
        #pragma unroll
        for (int r = 0; r < RPB; ++r) tmp[r] = X[(size_t)(r0 + r)*CIN + tid];
        #pragma unroll
        for (int j = 0; j < RPB/4; ++j)
            *(vfloat4*)&xsT[tid][4*j] = (vfloat4){tmp[4*j+0], tmp[4*j+1], tmp[4*j+2], tmp[4*j+3]};
    }
    __syncthreads();

    vfloat4 acc[RG];
    #pragma unroll
    for (int r = 0; r < RG; ++r) acc[r] = (vfloat4){0.f,0.f,0.f,0.f};
    const vfloat4* W4 = (const vfloat4*)W;
    #pragma unroll 4
    for (int k = 0; k < CIN; ++k) {
        vfloat4 w = W4[(size_t)k*64 + c4];                  // coalesced 1 KB/wave
        if constexpr (RG == 4) {
            vfloat4 xr = *(const vfloat4*)&xsT[k][rg*4];    // wave-uniform broadcast b128
            acc[0] += xr.x * w;
            acc[1] += xr.y * w;
            acc[2] += xr.z * w;
            acc[3] += xr.w * w;
        } else {
            vfloat2 xr = *(const vfloat2*)&xsT[k][rg*2];    // wave-uniform broadcast b64
            acc[0] += xr.x * w;
            acc[1] += xr.y * w;
        }
    }
    vfloat4 bb = ((const vfloat4*)Bv)[c4];
    vfloat4* D4 = (vfloat4*)D;
    const size_t rbase = (size_t)(r0 + rg*RG);
    #pragma unroll
    for (int r = 0; r < RG; ++r) D4[(rbase + r)*64 + c4] = acc[r] + bb;
}

// One block per (query i, batch b).
__global__ __launch_bounds__(256, 8) void attn_topk(
    const float* __restrict__ pg, const int* __restrict__ mask,
    const float* __restrict__ lW1g, const float* __restrict__ lb1g,
    const float* __restrict__ lW2g, const float* __restrict__ lb2g,
    const float* __restrict__ lW3g, const float* __restrict__ lb3g,
    const float* __restrict__ Q, const float* __restrict__ Kc, const float* __restrict__ Vc,
    float* __restrict__ O, float* __restrict__ pg_out, float* __restrict__ mask_out)
{
    const int i = blockIdx.x, b = blockIdx.y, tid = threadIdx.x;
    const int lane = tid & 63;

    // union: select phase -> hist[256] u32 @0, eqlist/candidates @256 ; later -> sc[64][8] f32
    __shared__ __align__(16) unsigned selbuf[512];   // 2 KB
    __shared__ float sg[MCS*7];                      // compact nbhd_g, stride 7
    __shared__ int nj[MCS];                          // bit31 = invalid flag
    __shared__ __align__(16) unsigned joff[MCS];     // float4 row offsets into Q/K/V space
    __shared__ vfloat4 obuf[4][64];                  // per-wave output partials (4 KB)
    __shared__ unsigned wsum[4];
    __shared__ unsigned sel_bin, sel_need, sel_cnt2, s_cnt, s_eqcnt, s_cand;

    float (*sc)[NH]   = (float (*)[NH])selbuf;
    unsigned* hist    = selbuf;
    unsigned* eqlist  = selbuf + 256;

    const int* mrow = mask + b*NN;
    // mask passthrough folded in; zero the candidate counter for the radix fast path
    if (tid == 0) { mask_out[b*NN + i] = mrow[i] ? 1.0f : 0.0f; s_cand = 0; }

    // ---- coalesced passthrough copy (nontemporal stores; pg_out never re-read) ----
    const size_t rowoff = (size_t)(b*NN + i) * (NN*GD);
    const vfloat4* src4 = (const vfloat4*)(pg + rowoff);
    vfloat4* dst4 = (vfloat4*)(pg_out + rowoff);
    #pragma unroll
    for (int t = 0; t < 6; ++t) {
        vfloat4 v = src4[tid + 256*t];
        __builtin_nontemporal_store(v, &dst4[tid + 256*t]);
    }
    // prefetch Q row quad (channels 4q..4q+3) for feat phase
    vfloat4 q4 = ((const vfloat4*)Q)[(size_t)(b*NN + i)*64 + (tid & 63)];

    // ---- per-thread rows j=4t..4t+3: 6 consecutive float4 (L2-warm), dist^2 in regs ----
    const int4 mv = ((const int4*)mrow)[tid];
    const vfloat4* gg = src4 + tid*6;
    vfloat4 g0 = gg[0], g1 = gg[1], g2 = gg[2], g3 = gg[3], g4 = gg[4], g5 = gg[5];
    float rv[4][6];
    rv[0][0]=g0.x; rv[0][1]=g0.y; rv[0][2]=g0.z; rv[0][3]=g0.w; rv[0][4]=g1.x; rv[0][5]=g1.y;
    rv[1][0]=g1.z; rv[1][1]=g1.w; rv[1][2]=g2.x; rv[1][3]=g2.y; rv[1][4]=g2.z; rv[1][5]=g2.w;
    rv[2][0]=g3.x; rv[2][1]=g3.y; rv[2][2]=g3.z; rv[2][3]=g3.w; rv[2][4]=g4.x; rv[2][5]=g4.y;
    rv[3][0]=g4.z; rv[3][1]=g4.w; rv[3][2]=g5.x; rv[3][3]=g5.y; rv[3][4]=g5.z; rv[3][5]=g5.w;
    const int vb[4] = { mv.x, mv.y, mv.z, mv.w };
    unsigned key[4];
    #pragma unroll
    for (int r = 0; r < 4; ++r) {
        float d2 = rv[r][0]*rv[r][0] + rv[r][1]*rv[r][1] + rv[r][2]*rv[r][2]
                 + rv[r][3]*rv[r][3] + rv[r][4]*rv[r][4] + rv[r][5]*rv[r][5];
        key[r] = __float_as_uint(vb[r] ? d2 : 1e30f);
    }

    // ---- radix select with early exit: refine 8 bits/level; once the selected
    //      bin holds <= 64 candidates, wave 0 finishes the selection exactly. ----
    unsigned prefix = 0;
    int need = MCS;
    unsigned T = 0;
    int needT = 0;
    for (int level = 0; level < 4; ++level) {
        const int shift = 24 - 8*level;
        hist[tid] = 0;
        __syncthreads();
        if (level == 0) {
            // digits cluster into few bins: ballot-clustered counting,
            // one atomic per distinct digit per wave.
            #pragma unroll
            for (int r = 0; r < 4; ++r) {
                unsigned d = key[r] >> 24;
                unsigned long long todo = __ballot(true);
                while (todo) {
                    int leader = (int)(__ffsll((unsigned long long)todo) - 1);
                    unsigned dl = __shfl(d, leader);
                    unsigned long long match = __ballot(d == dl);
                    if (lane == leader) atomicAdd(&hist[dl], (unsigned)__popcll(match));
                    todo &= ~match;
                }
            }
        } else {
            const unsigned pmask = 0xFFFFFFFFu << (shift + 8);
            #pragma unroll
            for (int r = 0; r < 4; ++r)
                if ((key[r] & pmask) == prefix)
                    atomicAdd(&hist[(key[r] >> shift) & 0xFFu], 1u);
        }
        __syncthreads();
        unsigned own = hist[tid];
        unsigned v = own;
        #pragma unroll
        for (int off = 1; off < 64; off <<= 1) {
            unsigned nv = __shfl_up(v, off);
            if (lane >= off) v += nv;
        }
        if (lane == 63) wsum[tid >> 6] = v;
        __syncthreads();
        unsigned basec = 0;
        for (int w = 0; w < (tid >> 6); ++w) basec += wsum[w];
        unsigned incl = v + basec;
        unsigned excl = incl - own;
        if (excl < (unsigned)need && (unsigned)need <= incl) {
            sel_bin  = (unsigned)tid;
            sel_need = (unsigned)need - excl;
            sel_cnt2 = own;                      // size of the selected bin
        }
        __syncthreads();
        prefix |= (sel_bin << shift);
        need = (int)sel_need;
        if (level == 3) { T = prefix; needT = need; break; }
        const int bincnt = (int)sel_cnt2;
        if (bincnt <= 64) {
            // fast path: gather the bin's candidates, rank them on wave 0
            const unsigned pmask = 0xFFFFFFFFu << shift;
            unsigned* ckey = selbuf + 256;       // aliases eqlist (dead until compaction)
            #pragma unroll
            for (int r = 0; r < 4; ++r) {
                if ((key[r] & pmask) == prefix) {
                    unsigned u = atomicAdd(&s_cand, 1u);
                    ckey[u] = key[r];
                }
            }
            __syncthreads();
            if (tid < 64) {
                unsigned myk = (tid < bincnt) ? ckey[tid] : 0xFFFFFFFFu;
                int rr = 0, ee = 0;
                for (int t = 0; t < bincnt; ++t) {   // bincnt typically 2-6
                    unsigned kt = __shfl(myk, t);
                    rr += (kt <  myk) ? 1 : 0;
                    ee += (kt == myk) ? 1 : 0;
                }
                if (tid < bincnt && rr < need && need <= rr + ee) {
                    sel_bin  = myk;                  // exact threshold key
                    sel_need = (unsigned)(need - rr);
                }
            }
            __syncthreads();
            T = sel_bin; needT = (int)sel_need;
            break;
        }
    }

    if (tid == 0) { s_cnt = 0; s_eqcnt = 0; }
    __syncthreads();
    // ---- compaction: owners scatter their selected rows straight into LDS ----
    #pragma unroll
    for (int r = 0; r < 4; ++r) {
        unsigned kk = key[r];
        int j = tid*4 + r;
        if (kk < T) {
            unsigned p = atomicAdd(&s_cnt, 1u);
            nj[p] = j | (vb[r] ? 0 : (int)0x80000000);
            #pragma unroll
            for (int g = 0; g < GD; ++g) sg[p*7 + g] = rv[r][g];
        } else if (kk == T) {
            unsigned e = atomicAdd(&s_eqcnt, 1u);
            if (e < 64) eqlist[e] = (unsigned)j;
        }
    }
    __syncthreads();
    const int cbase = (int)s_cnt;
    if (tid == 0) {
        int ec = (int)s_eqcnt; if (ec > 64) ec = 64;
        for (int s2 = 0; s2 < needT; ++s2) {
            int bi = -1, bj = 0x7FFFFFFF;
            for (int e = 0; e < ec; ++e) {
                int jj = (int)eqlist[e];
                if (jj < bj) { bj = jj; bi = e; }
            }
            if (bi >= 0) {
                eqlist[bi] = 0x7FFFFFFFu;
                nj[cbase + s2] = bj | (mrow[bj] ? 0 : (int)0x80000000);
            }
        }
    }
    __syncthreads();
    // owners of tie keys fill the g-values for the tie slots (needT is tiny)
    #pragma unroll
    for (int r = 0; r < 4; ++r) {
        if (key[r] == T) {
            int j = tid*4 + r;
            for (int s2 = 0; s2 < needT; ++s2)
                if ((nj[cbase + s2] & 0x7FFFFFFF) == j) {
                    #pragma unroll
                    for (int g = 0; g < GD; ++g) sg[(cbase + s2)*7 + g] = rv[r][g];
                }
        }
    }
    if (tid < MCS) joff[tid] = ((unsigned)(b*NN + (nj[tid] & 0x7FFFFFFF))) << 6;
    __syncthreads();   // nj+sg+joff ready; selbuf now reusable as sc[][]

    __builtin_amdgcn_s_setprio(1);
    // ---- location-kernel MLP: wave-uniform head -> scalar (s_load) weights ----
    #pragma unroll
    for (int pass = 0; pass < 2; ++pass) {
        const int h = __builtin_amdgcn_readfirstlane((tid >> 6) + pass*4);   // 0..7
        const int m = lane;
        const float* W1h = lW1g + h*(GD*HID);
        const float* B1h = lb1g + h*HID;
        const float* W2h = lW2g + h*(HID*HID);
        const float* B2h = lb2g + h*HID;
        const float* W3h = lW3g + h*HID;
        float gv[GD];
        #pragma unroll
        for (int g = 0; g < GD; ++g) gv[g] = sg[m*7 + g];
        float h1[HID];
        #pragma unroll
        for (int kk = 0; kk < HID; ++kk) {
            float a = B1h[kk];
            #pragma unroll
            for (int g = 0; g < GD; ++g) a += gv[g] * W1h[g*HID + kk];
            h1[kk] = swishf(a);
        }
        float h2[HID];
        #pragma unroll
        for (int l = 0; l < HID; ++l) {
            float a = B2h[l];
            #pragma unroll
            for (int kk = 0; kk < HID; ++kk) a += h1[kk] * W2h[kk*HID + l];
            h2[l] = swishf(a);
        }
        float a3 = lb3g[h];
        #pragma unroll
        for (int kk = 0; kk < HID; ++kk) a3 += h2[kk] * W3h[kk];
        sc[m][h] = (nj[m] < 0) ? -1e38f : swishf(a3);
    }
    __syncthreads();

    // ---- feat: wave p owns m = 16p..16p+15; lane q owns channel quad 4q..4q+3.
    //      4 K-row loads issued back-to-back (ILP-4 on the gather latency). ----
    const int q = tid & 63;
    const int p = tid >> 6;
    const int hh = q >> 3;                 // head of this channel quad
    q4 *= 0.17677669529663688f;            // fold 1/sqrt(32) into q
    const vfloat4* Kc4 = (const vfloat4*)Kc;
    const vuint4* jo4 = (const vuint4*)(joff + (p << 4));
    #pragma unroll
    for (int mg = 0; mg < 4; ++mg) {
        vuint4 o4 = jo4[mg];
        vfloat4 kv0 = Kc4[o4.x + (unsigned)q];
        vfloat4 kv1 = Kc4[o4.y + (unsigned)q];
        vfloat4 kv2 = Kc4[o4.z + (unsigned)q];
        vfloat4 kv3 = Kc4[o4.w + (unsigned)q];
        const int mb = (p << 4) + (mg << 2);
        #define FEAT_RED(KV, RR) do { \
            float d = q4.x * (KV).x; \
            d = fmaf(q4.y, (KV).y, d); \
            d = fmaf(q4.z, (KV).z, d); \
            d = fmaf(q4.w, (KV).w, d); \
            d += __shfl_xor(d, 1); \
            d += __shfl_xor(d, 2); \
            d += __shfl_xor(d, 4); \
            if ((q & 7) == 0) sc[mb + (RR)][hh] += d; \
        } while (0)
        FEAT_RED(kv0, 0); FEAT_RED(kv1, 1); FEAT_RED(kv2, 2); FEAT_RED(kv3, 3);
        #undef FEAT_RED
    }
    __syncthreads();

    // ---- softmax over m, wave-parallel: lane = m, wave (x2 passes) = head ----
    #pragma unroll
    for (int pass = 0; pass < 2; ++pass) {
        int h = (tid >> 6) + pass*4;
        float s = sc[lane][h];
        float mx = s;
        #pragma unroll
        for (int off = 32; off; off >>= 1) mx = fmaxf(mx, __shfl_xor(mx, off));
        float e = fast_exp2((s - mx) * LOG2E);
        float sum = e;
        #pragma unroll
        for (int off = 32; off; off >>= 1) sum += __shfl_xor(sum, off);
        sc[lane][h] = e * fast_rcp(sum);
    }
    __syncthreads();

    // ---- out: same partition; 4 V-row loads batched; 4 wave-partials reduced in LDS ----
    {
        const vfloat4* Vc4 = (const vfloat4*)Vc;
        vfloat4 acc = (vfloat4){0.f,0.f,0.f,0.f};
        #pragma unroll
        for (int mg = 0; mg < 4; ++mg) {
            vuint4 o4 = jo4[mg];
            vfloat4 v0 = Vc4[o4.x + (unsigned)q];
            vfloat4 v1 = Vc4[o4.y + (unsigned)q];
            vfloat4 v2 = Vc4[o4.z + (unsigned)q];
            vfloat4 v3 = Vc4[o4.w + (unsigned)q];
            const int mb = (p << 4) + (mg << 2);
            float a0 = sc[mb + 0][hh];
            float a1 = sc[mb + 1][hh];
            float a2 = sc[mb + 2][hh];
            float a3 = sc[mb + 3][hh];
            acc += a0 * v0;
            acc += a1 * v1;
            acc += a2 * v2;
            acc += a3 * v3;
        }
        __builtin_amdgcn_s_setprio(0);
        obuf[p][q] = acc;
    }
    __syncthreads();
    {
        const float* ob = (const float*)obuf;
        float s = ob[tid] + ob[256 + tid] + ob[512 + tid] + ob[768 + tid];
        O[(size_t)(b*NN + i)*CIN + tid] = s;
    }
}

extern "C" void kernel_launch(void* const* d_in, const int* in_sizes, int n_in,
                              void* d_out, int out_size, void* d_ws, size_t ws_size,
                              hipStream_t stream) {
    const float* pg   = (const float*)d_in[0];
    const float* x    = (const float*)d_in[1];
    const int*   mask = (const int*)d_in[2];
    const float* lW1  = (const float*)d_in[3];
    const float* lb1  = (const float*)d_in[4];
    const float* lW2  = (const float*)d_in[5];
    const float* lb2  = (const float*)d_in[6];
    const float* lW3  = (const float*)d_in[7];
    const float* lb3  = (const float*)d_in[8];
    const float* Wq   = (const float*)d_in[9];
    const float* bq   = (const float*)d_in[10];
    const float* Wk   = (const float*)d_in[11];
    const float* bk   = (const float*)d_in[12];
    const float* Wv   = (const float*)d_in[13];
    const float* bv   = (const float*)d_in[14];
    const float* Wo   = (const float*)d_in[15];
    const float* bo   = (const float*)d_in[16];

    float* out = (float*)d_out;
    float* Q  = (float*)d_ws;
    float* Kc = Q  + (size_t)BS*NN*CIN;
    float* Vc = Kc + (size_t)BS*NN*CIN;
    float* O  = Vc + (size_t)BS*NN*CIN;

    // QKV projections (z = 0,1,2)
    gemm3<16><<<dim3(BS*NN/16, 3), 256, 0, stream>>>(x, Wq, bq, Q, Wk, bk, Kc, Wv, bv, Vc);
    // top-k + attention (also performs the pairwise_g passthrough copy + mask write)
    attn_topk<<<dim3(NN, BS), 256, 0, stream>>>(pg, mask, lW1, lb1, lW2, lb2, lW3, lb3,
                                                Q, Kc, Vc, O, out, out + MASK_OFF);
    // output projection: 8 rows/block -> 512 blocks -> 2 blocks/CU (was 1, latency-exposed)
    gemm3<8><<<dim3(BS*NN/8, 1), 256, 0, stream>>>(O, Wo, bo, out + OUT_OFF,
                                                   Wo, bo, out + OUT_OFF,
                                                   Wo, bo, out + OUT_OFF);
}